// Round 1
// baseline (2550.645 us; speedup 1.0000x reference)
//
#include <hip/hip_runtime.h>
#include <math.h>

namespace {

constexpr int Bn  = 16;
constexpr int Cn  = 256;
constexpr int C8n = 32;

// ---------------------------------------------------------------------------
// Kernel: fused q/k projection.  out q[b][32][Npix], k[b][32][Npix].
// GEMM: 64 output channels (32 q + 32 k) x 128 pixels per block, K=256.
// grid: (Npix/128, B), block 256.
// ---------------------------------------------------------------------------
__global__ __launch_bounds__(256) void qk_proj_kernel(
    const float* __restrict__ x,      // [B][C][Npix]
    const float* __restrict__ qw,     // [C8][C]
    const float* __restrict__ qbias,  // [C8]
    const float* __restrict__ kw,
    const float* __restrict__ kbias,
    float* __restrict__ qo,           // [B][C8][Npix]
    float* __restrict__ ko,
    int Npix)
{
    __shared__ float xs[64][128];
    __shared__ float ws[64][68];   // [k][o] transposed (+pad)
    const int t  = threadIdx.x;
    const int b  = blockIdx.y;
    const int p0 = blockIdx.x * 128;
    const int tx = t & 31;     // 4 pixels each -> 128
    const int ty = t >> 5;     // 8 groups of 8 out-channels
    float acc[8][4];
#pragma unroll
    for (int i = 0; i < 8; ++i)
#pragma unroll
        for (int j = 0; j < 4; ++j) acc[i][j] = 0.f;

    const float* xb  = x + (size_t)b * Cn * Npix;
    const int skk = t & 63, sor = t >> 6;

    for (int k0 = 0; k0 < Cn; k0 += 64) {
        // stage x chunk [64][128] with float4 loads
#pragma unroll
        for (int r = 0; r < 8; ++r) {
            int idx = r * 256 + t;
            int kk = idx >> 5, pp = (idx & 31) * 4;
            *(float4*)&xs[kk][pp] =
                *(const float4*)&xb[(size_t)(k0 + kk) * Npix + p0 + pp];
        }
        // stage weights transposed: ws[k][o]
#pragma unroll
        for (int r = 0; r < 16; ++r) {
            int o = r * 4 + sor;
            const float* wsrc = (o < 32) ? (qw + (size_t)o * Cn)
                                         : (kw + (size_t)(o - 32) * Cn);
            ws[skk][o] = wsrc[k0 + skk];
        }
        __syncthreads();
#pragma unroll 4
        for (int kk = 0; kk < 64; ++kk) {
            float4 w0 = *(const float4*)&ws[kk][ty * 8];
            float4 w1 = *(const float4*)&ws[kk][ty * 8 + 4];
            float4 xv = *(const float4*)&xs[kk][tx * 4];
            float wv[8] = {w0.x, w0.y, w0.z, w0.w, w1.x, w1.y, w1.z, w1.w};
            float pv[4] = {xv.x, xv.y, xv.z, xv.w};
#pragma unroll
            for (int i = 0; i < 8; ++i)
#pragma unroll
                for (int j = 0; j < 4; ++j)
                    acc[i][j] = fmaf(wv[i], pv[j], acc[i][j]);
        }
        __syncthreads();
    }
#pragma unroll
    for (int i = 0; i < 8; ++i) {
        int o = ty * 8 + i;
        float bias;
        float* dst;
        if (o < 32) { bias = qbias[o];      dst = qo + ((size_t)b * C8n + o)        * Npix; }
        else        { bias = kbias[o - 32]; dst = ko + ((size_t)b * C8n + (o - 32)) * Npix; }
        float4 v4 = make_float4(acc[i][0] + bias, acc[i][1] + bias,
                                acc[i][2] + bias, acc[i][3] + bias);
        *(float4*)&dst[p0 + tx * 4] = v4;
    }
}

// ---------------------------------------------------------------------------
// Kernel: attention energy over W.  e[b][w][v] = sum_f q[b][f][w]*k[b][f][v],
// f = o*P+h (feature-major layout matches q memory layout exactly).
// Split-K over gridDim.z=8 slices, partials to epart[8][B][P][P].
// grid: ((P/64)^2, B, 8), block 256, tile 64x64, acc 4x4.
// ---------------------------------------------------------------------------
__global__ __launch_bounds__(256) void energy_w_kernel(
    const float* __restrict__ q,   // [B][K][P], K = C8*P
    const float* __restrict__ k,
    float* __restrict__ epart,     // [8][B][P][P]
    int P, int KL)                 // KL = K/8
{
    __shared__ float qs[32][64];
    __shared__ float ks[32][64];
    const int t  = threadIdx.x;
    const int nt = P >> 6;
    const int tw = blockIdx.x / nt;
    const int tv = blockIdx.x % nt;
    const int b  = blockIdx.y;
    const int z  = blockIdx.z;
    const int w0 = tw * 64, v0 = tv * 64;
    const int Ktot = KL * 8;
    const float* qb = q + ((size_t)b * Ktot + (size_t)z * KL) * P;
    const float* kb = k + ((size_t)b * Ktot + (size_t)z * KL) * P;
    const int tx = t & 15, ty = t >> 4;
    float acc[4][4];
#pragma unroll
    for (int i = 0; i < 4; ++i)
#pragma unroll
        for (int j = 0; j < 4; ++j) acc[i][j] = 0.f;

    for (int kc = 0; kc < KL; kc += 32) {
#pragma unroll
        for (int r = 0; r < 8; ++r) {
            int idx = r * 256 + t;
            int kk = idx >> 6, col = idx & 63;
            qs[kk][col] = qb[(size_t)(kc + kk) * P + w0 + col];
            ks[kk][col] = kb[(size_t)(kc + kk) * P + v0 + col];
        }
        __syncthreads();
#pragma unroll 8
        for (int kk = 0; kk < 32; ++kk) {
            float4 qv = *(const float4*)&qs[kk][ty * 4];
            float4 kv = *(const float4*)&ks[kk][tx * 4];
            float qa[4] = {qv.x, qv.y, qv.z, qv.w};
            float ka[4] = {kv.x, kv.y, kv.z, kv.w};
#pragma unroll
            for (int i = 0; i < 4; ++i)
#pragma unroll
                for (int j = 0; j < 4; ++j)
                    acc[i][j] = fmaf(qa[i], ka[j], acc[i][j]);
        }
        __syncthreads();
    }
#pragma unroll
    for (int i = 0; i < 4; ++i) {
        size_t off = (((size_t)z * Bn + b) * P + (w0 + ty * 4 + i)) * P + v0 + tx * 4;
        *(float4*)&epart[off] = make_float4(acc[i][0], acc[i][1], acc[i][2], acc[i][3]);
    }
}

// ---------------------------------------------------------------------------
// Kernel: attention energy over H.  e[b][h][v] = sum_{o,w} q[b][o][h][w]*k[b][o][v][w].
// Feature = (o,w): stage tiles transposed so compute uses float4 LDS reads.
// Split-K over o: gridDim.z=8 slices of 4 o's each.
// grid: ((P/64)^2, B, 8), block 256, tile 64x64.
// ---------------------------------------------------------------------------
__global__ __launch_bounds__(256) void energy_h_kernel(
    const float* __restrict__ q,   // [B][C8][P][P]
    const float* __restrict__ k,
    float* __restrict__ epart,     // [8][B][P][P]
    int P)
{
    __shared__ float qsT[64][68];  // [w][h]
    __shared__ float ksT[64][68];  // [w][v]
    const int t  = threadIdx.x;
    const int nt = P >> 6;
    const int th = blockIdx.x / nt;
    const int tv = blockIdx.x % nt;
    const int b  = blockIdx.y;
    const int z  = blockIdx.z;
    const int h0 = th * 64, v0 = tv * 64;
    const int o0 = z * (C8n / 8);
    const int tx = t & 15, ty = t >> 4;
    const int ww = t & 63, hh0 = t >> 6;
    float acc[4][4];
#pragma unroll
    for (int i = 0; i < 4; ++i)
#pragma unroll
        for (int j = 0; j < 4; ++j) acc[i][j] = 0.f;

    for (int o = o0; o < o0 + 4; ++o) {
        const float* qo = q + ((size_t)(b * C8n + o)) * P * P;
        const float* ko = k + ((size_t)(b * C8n + o)) * P * P;
        for (int wc = 0; wc < P; wc += 64) {
#pragma unroll
            for (int r = 0; r < 16; ++r) {
                int hh = r * 4 + hh0;
                qsT[ww][hh] = qo[(size_t)(h0 + hh) * P + wc + ww];
                ksT[ww][hh] = ko[(size_t)(v0 + hh) * P + wc + ww];
            }
            __syncthreads();
#pragma unroll 8
            for (int kk = 0; kk < 64; ++kk) {
                float4 qv = *(const float4*)&qsT[kk][ty * 4];
                float4 kv = *(const float4*)&ksT[kk][tx * 4];
                float qa[4] = {qv.x, qv.y, qv.z, qv.w};
                float ka[4] = {kv.x, kv.y, kv.z, kv.w};
#pragma unroll
                for (int i = 0; i < 4; ++i)
#pragma unroll
                    for (int j = 0; j < 4; ++j)
                        acc[i][j] = fmaf(qa[i], ka[j], acc[i][j]);
            }
            __syncthreads();
        }
    }
#pragma unroll
    for (int i = 0; i < 4; ++i) {
        size_t off = (((size_t)z * Bn + b) * P + (h0 + ty * 4 + i)) * P + v0 + tx * 4;
        *(float4*)&epart[off] = make_float4(acc[i][0], acc[i][1], acc[i][2], acc[i][3]);
    }
}

// ---------------------------------------------------------------------------
// Kernel: row softmax with split-K reduction. One wave per row.
// grid: B*P, block 64.
// ---------------------------------------------------------------------------
template <int P>
__global__ __launch_bounds__(64) void softmax_kernel(
    const float* __restrict__ epart,  // [8][B][P][P]
    float* __restrict__ a)            // [B][P][P]
{
    const int row  = blockIdx.x;      // b*P + i
    const int lane = threadIdx.x;
    constexpr int E = P / 64;
    float e[E];
#pragma unroll
    for (int j = 0; j < E; ++j) {
        int v = lane + j * 64;
        float s = 0.f;
#pragma unroll
        for (int z = 0; z < 8; ++z)
            s += epart[((size_t)z * Bn * P + row) * P + v];
        e[j] = s;
    }
    float m = e[0];
#pragma unroll
    for (int j = 1; j < E; ++j) m = fmaxf(m, e[j]);
    for (int off = 32; off > 0; off >>= 1) m = fmaxf(m, __shfl_xor(m, off));
    float sum = 0.f;
#pragma unroll
    for (int j = 0; j < E; ++j) { e[j] = __expf(e[j] - m); sum += e[j]; }
    for (int off = 32; off > 0; off >>= 1) sum += __shfl_xor(sum, off);
    float inv = 1.0f / sum;
#pragma unroll
    for (int j = 0; j < E; ++j)
        a[(size_t)row * P + lane + j * 64] = e[j] * inv;
}

// ---------------------------------------------------------------------------
// Kernel: mix over W.  y[b][m][w] = sum_v x[b][m][v] * a[b][w][v],  m in [0,C*P).
// Batched GEMM, M=C*P, N=P, K=P.  Tile 64 rows x P cols.
// grid: (C*P/64, B), block 256.
// ---------------------------------------------------------------------------
template <int P>
__global__ __launch_bounds__(256) void mix_w_kernel(
    const float* __restrict__ x,   // [B][M][P]
    const float* __restrict__ a,   // [B][P][P]
    float* __restrict__ y)         // [B][M][P]
{
    constexpr int WT = P / 4;        // threads along w (16/32)
    constexpr int MT = 256 / WT;     // thread groups along m (16/8)
    constexpr int MR = 64 / MT;      // rows per thread (4/8)
    __shared__ float xsT[32][68];        // [v][m]
    __shared__ float at[32][P + 4];      // [v][w]
    const int t  = threadIdx.x;
    const int b  = blockIdx.y;
    const int m0 = blockIdx.x * 64;
    const int M  = Cn * P;
    const int tx = t % WT, ty = t / WT;
    float acc[MR][4];
#pragma unroll
    for (int i = 0; i < MR; ++i)
#pragma unroll
        for (int j = 0; j < 4; ++j) acc[i][j] = 0.f;

    const float* xb = x + (size_t)b * M * P;
    const float* ab = a + (size_t)b * P * P;
    const int vv = t & 31, r8 = t >> 5;

    for (int vc = 0; vc < P; vc += 32) {
#pragma unroll
        for (int r = 0; r < 8; ++r) {
            int mm = r * 8 + r8;
            xsT[vv][mm] = xb[(size_t)(m0 + mm) * P + vc + vv];
        }
#pragma unroll
        for (int r = 0; r < P / 8; ++r) {
            int w = r * 8 + r8;
            at[vv][w] = ab[(size_t)w * P + vc + vv];
        }
        __syncthreads();
#pragma unroll 4
        for (int kk = 0; kk < 32; ++kk) {
            float4 av = *(const float4*)&at[kk][tx * 4];
            float aw[4] = {av.x, av.y, av.z, av.w};
            float xr[MR];
#pragma unroll
            for (int i = 0; i < MR; i += 4) {
                float4 xv = *(const float4*)&xsT[kk][ty * MR + i];
                xr[i] = xv.x; xr[i + 1] = xv.y; xr[i + 2] = xv.z; xr[i + 3] = xv.w;
            }
#pragma unroll
            for (int i = 0; i < MR; ++i)
#pragma unroll
                for (int j = 0; j < 4; ++j)
                    acc[i][j] = fmaf(xr[i], aw[j], acc[i][j]);
        }
        __syncthreads();
    }
#pragma unroll
    for (int i = 0; i < MR; ++i) {
        size_t off = ((size_t)b * M + m0 + ty * MR + i) * P + tx * 4;
        *(float4*)&y[off] = make_float4(acc[i][0], acc[i][1], acc[i][2], acc[i][3]);
    }
}

// ---------------------------------------------------------------------------
// Kernel: mix over H.  y[b][c][h][w] = sum_v a[b][h][v] * x[b][c][v][w].
// Per (b,c,h-tile): GEMM tile [TILE_H x P], K = P.
// grid: (C * P/TILE_H, B), block 256.
// ---------------------------------------------------------------------------
template <int P>
__global__ __launch_bounds__(256) void mix_h_kernel(
    const float* __restrict__ x,   // [B][C][P][P]
    const float* __restrict__ a,   // [B][P][P]
    float* __restrict__ y)
{
    constexpr int WT = P / 4;          // 32/16
    constexpr int HT = 256 / WT;       // 8/16
    constexpr int TILE_H = HT * 4;     // 32/64
    __shared__ float xs[32][P];            // [v][w]
    __shared__ float at2[32][TILE_H + 4];  // [v][h]
    const int t  = threadIdx.x;
    const int b  = blockIdx.y;
    const int nh = P / TILE_H;
    const int c  = blockIdx.x / nh;
    const int h0 = (blockIdx.x % nh) * TILE_H;
    const int tx = t % WT, ty = t / WT;
    float acc[4][4];
#pragma unroll
    for (int i = 0; i < 4; ++i)
#pragma unroll
        for (int j = 0; j < 4; ++j) acc[i][j] = 0.f;

    const float* xc = x + ((size_t)(b * Cn + c)) * P * P;
    const float* ab = a + (size_t)b * P * P;
    const int ww = t % P, vr = t / P;
    const int vv = t & 31, hr = t >> 5;

    for (int vc = 0; vc < P; vc += 32) {
#pragma unroll
        for (int r = 0; r < 32 * P / 256; ++r) {
            int vvv = r * (256 / P) + vr;
            xs[vvv][ww] = xc[(size_t)(vc + vvv) * P + ww];
        }
#pragma unroll
        for (int r = 0; r < TILE_H / 8; ++r) {
            int hh = r * 8 + hr;
            at2[vv][hh] = ab[(size_t)(h0 + hh) * P + vc + vv];
        }
        __syncthreads();
#pragma unroll 4
        for (int kk = 0; kk < 32; ++kk) {
            float4 xv = *(const float4*)&xs[kk][tx * 4];
            float4 av = *(const float4*)&at2[kk][ty * 4];
            float xa[4] = {xv.x, xv.y, xv.z, xv.w};
            float aa[4] = {av.x, av.y, av.z, av.w};
#pragma unroll
            for (int i = 0; i < 4; ++i)
#pragma unroll
                for (int j = 0; j < 4; ++j)
                    acc[i][j] = fmaf(aa[i], xa[j], acc[i][j]);
        }
        __syncthreads();
    }
#pragma unroll
    for (int i = 0; i < 4; ++i) {
        size_t off = ((size_t)(b * Cn + c) * P + h0 + ty * 4 + i) * P + tx * 4;
        *(float4*)&y[off] = make_float4(acc[i][0], acc[i][1], acc[i][2], acc[i][3]);
    }
}

// ---------------------------------------------------------------------------
// Kernel: final V projection fused with scale + bias + residual accumulate.
// first=1: out = 2*x + s*(vw.y + vb);  first=0: out += s*(vw.y + vb)
// grid: (Npix/128, C/64, B), block 256.
// ---------------------------------------------------------------------------
__global__ __launch_bounds__(256) void vproj_final_kernel(
    const float* __restrict__ y,    // [B][C][Npix]
    const float* __restrict__ vw,   // [C][C]
    const float* __restrict__ vb,   // [C]
    const float* __restrict__ x,    // [B][C][Npix]
    float* __restrict__ out,
    const float* __restrict__ scal, int si,
    int first, int Npix)
{
    __shared__ float ys[64][128];
    __shared__ float wvs[64][68];   // [k][c] transposed
    const int t  = threadIdx.x;
    const int p0 = blockIdx.x * 128;
    const int c0 = blockIdx.y * 64;
    const int b  = blockIdx.z;
    const int tx = t & 31, ty = t >> 5;
    float acc[8][4];
#pragma unroll
    for (int i = 0; i < 8; ++i)
#pragma unroll
        for (int j = 0; j < 4; ++j) acc[i][j] = 0.f;

    const float* yb = y + (size_t)b * Cn * Npix;
    const int skk = t & 63, scr = t >> 6;

    for (int k0 = 0; k0 < Cn; k0 += 64) {
#pragma unroll
        for (int r = 0; r < 8; ++r) {
            int idx = r * 256 + t;
            int kk = idx >> 5, pp = (idx & 31) * 4;
            *(float4*)&ys[kk][pp] =
                *(const float4*)&yb[(size_t)(k0 + kk) * Npix + p0 + pp];
        }
#pragma unroll
        for (int r = 0; r < 16; ++r) {
            int cc = r * 4 + scr;
            wvs[skk][cc] = vw[(size_t)(c0 + cc) * Cn + k0 + skk];
        }
        __syncthreads();
#pragma unroll 4
        for (int kk = 0; kk < 64; ++kk) {
            float4 w0 = *(const float4*)&wvs[kk][ty * 8];
            float4 w1 = *(const float4*)&wvs[kk][ty * 8 + 4];
            float4 yv = *(const float4*)&ys[kk][tx * 4];
            float wv8[8] = {w0.x, w0.y, w0.z, w0.w, w1.x, w1.y, w1.z, w1.w};
            float pv[4]  = {yv.x, yv.y, yv.z, yv.w};
#pragma unroll
            for (int i = 0; i < 8; ++i)
#pragma unroll
                for (int j = 0; j < 4; ++j)
                    acc[i][j] = fmaf(wv8[i], pv[j], acc[i][j]);
        }
        __syncthreads();
    }
    const float s = scal[si];
#pragma unroll
    for (int i = 0; i < 8; ++i) {
        int c = c0 + ty * 8 + i;
        float bias = vb[c];
        size_t off = ((size_t)(b * Cn + c)) * Npix + p0 + tx * 4;
        float4 res = make_float4(s * (acc[i][0] + bias), s * (acc[i][1] + bias),
                                 s * (acc[i][2] + bias), s * (acc[i][3] + bias));
        if (first) {
            float4 xv = *(const float4*)&x[off];
            res.x += 2.f * xv.x; res.y += 2.f * xv.y;
            res.z += 2.f * xv.z; res.w += 2.f * xv.w;
        } else {
            float4 ov = *(const float4*)&out[off];
            res.x += ov.x; res.y += ov.y; res.z += ov.z; res.w += ov.w;
        }
        *(float4*)&out[off] = res;
    }
}

struct Bufs {
    float* E;  // [8][B][128][128]   2,097,152 floats
    float* A;  // [B][128][128]        262,144 floats
    float* Y;  // [B][C][128][128]  67,108,864 floats
    float* Q;  // aliases head of Y (dead when Y live)
    float* K;
};

void run_image(const float* x, float* out, int P, int brW, int brH,
               const float* qw, const float* qb, const float* kw, const float* kb,
               const float* vw, const float* vb, const float* sc,
               const Bufs& w, hipStream_t stream)
{
    const int Npix = P * P;
    const int Kfeat = C8n * P;
    dim3 blk(256);

    for (int half = 0; half < 2; ++half) {
        const int br = half == 0 ? brW : brH;
        // q/k projection
        qk_proj_kernel<<<dim3(Npix / 128, Bn), blk, 0, stream>>>(
            x, qw + (size_t)br * C8n * Cn, qb + (size_t)br * C8n,
            kw + (size_t)br * C8n * Cn, kb + (size_t)br * C8n,
            w.Q, w.K, Npix);
        // energy (split-K partials)
        dim3 eg((P / 64) * (P / 64), Bn, 8);
        if (half == 0)
            energy_w_kernel<<<eg, blk, 0, stream>>>(w.Q, w.K, w.E, P, Kfeat / 8);
        else
            energy_h_kernel<<<eg, blk, 0, stream>>>(w.Q, w.K, w.E, P);
        // softmax
        if (P == 64)
            softmax_kernel<64><<<Bn * P, 64, 0, stream>>>(w.E, w.A);
        else
            softmax_kernel<128><<<Bn * P, 64, 0, stream>>>(w.E, w.A);
        // position mix of raw x by attention matrix
        if (half == 0) {
            if (P == 64)
                mix_w_kernel<64><<<dim3(Cn * P / 64, Bn), blk, 0, stream>>>(x, w.A, w.Y);
            else
                mix_w_kernel<128><<<dim3(Cn * P / 64, Bn), blk, 0, stream>>>(x, w.A, w.Y);
        } else {
            if (P == 64)
                mix_h_kernel<64><<<dim3(Cn * (P / 64), Bn), blk, 0, stream>>>(x, w.A, w.Y);
            else
                mix_h_kernel<128><<<dim3(Cn * (P / 32), Bn), blk, 0, stream>>>(x, w.A, w.Y);
        }
        // fused v-projection + scale + bias + residual
        vproj_final_kernel<<<dim3(Npix / 128, Cn / 64, Bn), blk, 0, stream>>>(
            w.Y, vw + (size_t)br * Cn * Cn, vb + (size_t)br * Cn,
            x, out, sc, br, half == 0 ? 1 : 0, Npix);
    }
}

}  // namespace

extern "C" void kernel_launch(void* const* d_in, const int* in_sizes, int n_in,
                              void* d_out, int out_size, void* d_ws, size_t ws_size,
                              hipStream_t stream) {
    (void)in_sizes; (void)n_in; (void)out_size; (void)ws_size;
    const float* tmap = (const float*)d_in[0];
    const float* smap = (const float*)d_in[1];
    const float* qw   = (const float*)d_in[2];
    const float* qb   = (const float*)d_in[3];
    const float* kw   = (const float*)d_in[4];
    const float* kb   = (const float*)d_in[5];
    const float* vw   = (const float*)d_in[6];
    const float* vb   = (const float*)d_in[7];
    const float* sc   = (const float*)d_in[8];

    float* out0 = (float*)d_out;                       // [16,256,64,64]
    float* out1 = out0 + (size_t)16 * 256 * 64 * 64;   // [16,256,128,128]

    // Workspace layout (floats). Q/K alias the start of Y: q/k are dead once
    // the energy kernel has consumed them, before mix writes Y.
    // Total: 2,097,152 + 262,144 + 67,108,864 = 69,468,160 floats = 278 MB.
    float* f = (float*)d_ws;
    Bufs w;
    w.E = f;
    w.A = w.E + (size_t)8 * Bn * 128 * 128;
    w.Y = w.A + (size_t)Bn * 128 * 128;
    w.Q = w.Y;
    w.K = w.Y + (size_t)Bn * C8n * 128 * 128;

    // template: P=64, branches 0 (over W) and 2 (over H)
    run_image(tmap, out0, 64, 0, 2, qw, qb, kw, kb, vw, vb, sc, w, stream);
    // scene: P=128, branches 1 (over W) and 3 (over H)
    run_image(smap, out1, 128, 1, 3, qw, qb, kw, kb, vw, vb, sc, w, stream);
}

// Round 2
// 1721.718 us; speedup vs baseline: 1.4815x; 1.4815x over previous
//
#include <hip/hip_runtime.h>
#include <math.h>

namespace {

constexpr int Bn  = 16;
constexpr int Cn  = 256;
constexpr int C8n = 32;

typedef __attribute__((ext_vector_type(8))) __bf16 bf16x8;
typedef __attribute__((ext_vector_type(4))) __bf16 bf16x4;
typedef __attribute__((ext_vector_type(4))) float  floatx4;

// ---------------------------------------------------------------------------
// fp32 q/k projection (unchanged from round 1).
// grid: (Npix/128, B), block 256.
// ---------------------------------------------------------------------------
__global__ __launch_bounds__(256) void qk_proj_kernel(
    const float* __restrict__ x,      // [B][C][Npix]
    const float* __restrict__ qw,     // [C8][C]
    const float* __restrict__ qbias,  // [C8]
    const float* __restrict__ kw,
    const float* __restrict__ kbias,
    float* __restrict__ qo,           // [B][C8][Npix]
    float* __restrict__ ko,
    int Npix)
{
    __shared__ float xs[64][128];
    __shared__ float ws[64][68];
    const int t  = threadIdx.x;
    const int b  = blockIdx.y;
    const int p0 = blockIdx.x * 128;
    const int tx = t & 31;
    const int ty = t >> 5;
    float acc[8][4];
#pragma unroll
    for (int i = 0; i < 8; ++i)
#pragma unroll
        for (int j = 0; j < 4; ++j) acc[i][j] = 0.f;

    const float* xb  = x + (size_t)b * Cn * Npix;
    const int skk = t & 63, sor = t >> 6;

    for (int k0 = 0; k0 < Cn; k0 += 64) {
#pragma unroll
        for (int r = 0; r < 8; ++r) {
            int idx = r * 256 + t;
            int kk = idx >> 5, pp = (idx & 31) * 4;
            *(float4*)&xs[kk][pp] =
                *(const float4*)&xb[(size_t)(k0 + kk) * Npix + p0 + pp];
        }
#pragma unroll
        for (int r = 0; r < 16; ++r) {
            int o = r * 4 + sor;
            const float* wsrc = (o < 32) ? (qw + (size_t)o * Cn)
                                         : (kw + (size_t)(o - 32) * Cn);
            ws[skk][o] = wsrc[k0 + skk];
        }
        __syncthreads();
#pragma unroll 4
        for (int kk = 0; kk < 64; ++kk) {
            float4 w0 = *(const float4*)&ws[kk][ty * 8];
            float4 w1 = *(const float4*)&ws[kk][ty * 8 + 4];
            float4 xv = *(const float4*)&xs[kk][tx * 4];
            float wv[8] = {w0.x, w0.y, w0.z, w0.w, w1.x, w1.y, w1.z, w1.w};
            float pv[4] = {xv.x, xv.y, xv.z, xv.w};
#pragma unroll
            for (int i = 0; i < 8; ++i)
#pragma unroll
                for (int j = 0; j < 4; ++j)
                    acc[i][j] = fmaf(wv[i], pv[j], acc[i][j]);
        }
        __syncthreads();
    }
#pragma unroll
    for (int i = 0; i < 8; ++i) {
        int o = ty * 8 + i;
        float bias;
        float* dst;
        if (o < 32) { bias = qbias[o];      dst = qo + ((size_t)b * C8n + o)        * Npix; }
        else        { bias = kbias[o - 32]; dst = ko + ((size_t)b * C8n + (o - 32)) * Npix; }
        float4 v4 = make_float4(acc[i][0] + bias, acc[i][1] + bias,
                                acc[i][2] + bias, acc[i][3] + bias);
        *(float4*)&dst[p0 + tx * 4] = v4;
    }
}

// ---------------------------------------------------------------------------
// fp32 energy over W (unchanged). grid ((P/64)^2, B, 8).
// ---------------------------------------------------------------------------
__global__ __launch_bounds__(256) void energy_w_kernel(
    const float* __restrict__ q, const float* __restrict__ k,
    float* __restrict__ epart, int P, int KL)
{
    __shared__ float qs[32][64];
    __shared__ float ks[32][64];
    const int t  = threadIdx.x;
    const int nt = P >> 6;
    const int tw = blockIdx.x / nt;
    const int tv = blockIdx.x % nt;
    const int b  = blockIdx.y;
    const int z  = blockIdx.z;
    const int w0 = tw * 64, v0 = tv * 64;
    const int Ktot = KL * 8;
    const float* qb = q + ((size_t)b * Ktot + (size_t)z * KL) * P;
    const float* kb = k + ((size_t)b * Ktot + (size_t)z * KL) * P;
    const int tx = t & 15, ty = t >> 4;
    float acc[4][4];
#pragma unroll
    for (int i = 0; i < 4; ++i)
#pragma unroll
        for (int j = 0; j < 4; ++j) acc[i][j] = 0.f;

    for (int kc = 0; kc < KL; kc += 32) {
#pragma unroll
        for (int r = 0; r < 8; ++r) {
            int idx = r * 256 + t;
            int kk = idx >> 6, col = idx & 63;
            qs[kk][col] = qb[(size_t)(kc + kk) * P + w0 + col];
            ks[kk][col] = kb[(size_t)(kc + kk) * P + v0 + col];
        }
        __syncthreads();
#pragma unroll 8
        for (int kk = 0; kk < 32; ++kk) {
            float4 qv = *(const float4*)&qs[kk][ty * 4];
            float4 kv = *(const float4*)&ks[kk][tx * 4];
            float qa[4] = {qv.x, qv.y, qv.z, qv.w};
            float ka[4] = {kv.x, kv.y, kv.z, kv.w};
#pragma unroll
            for (int i = 0; i < 4; ++i)
#pragma unroll
                for (int j = 0; j < 4; ++j)
                    acc[i][j] = fmaf(qa[i], ka[j], acc[i][j]);
        }
        __syncthreads();
    }
#pragma unroll
    for (int i = 0; i < 4; ++i) {
        size_t off = (((size_t)z * Bn + b) * P + (w0 + ty * 4 + i)) * P + v0 + tx * 4;
        *(float4*)&epart[off] = make_float4(acc[i][0], acc[i][1], acc[i][2], acc[i][3]);
    }
}

// ---------------------------------------------------------------------------
// fp32 energy over H (unchanged). grid ((P/64)^2, B, 8).
// ---------------------------------------------------------------------------
__global__ __launch_bounds__(256) void energy_h_kernel(
    const float* __restrict__ q, const float* __restrict__ k,
    float* __restrict__ epart, int P)
{
    __shared__ float qsT[64][68];
    __shared__ float ksT[64][68];
    const int t  = threadIdx.x;
    const int nt = P >> 6;
    const int th = blockIdx.x / nt;
    const int tv = blockIdx.x % nt;
    const int b  = blockIdx.y;
    const int z  = blockIdx.z;
    const int h0 = th * 64, v0 = tv * 64;
    const int o0 = z * (C8n / 8);
    const int tx = t & 15, ty = t >> 4;
    const int ww = t & 63, hh0 = t >> 6;
    float acc[4][4];
#pragma unroll
    for (int i = 0; i < 4; ++i)
#pragma unroll
        for (int j = 0; j < 4; ++j) acc[i][j] = 0.f;

    for (int o = o0; o < o0 + 4; ++o) {
        const float* qo = q + ((size_t)(b * C8n + o)) * P * P;
        const float* ko = k + ((size_t)(b * C8n + o)) * P * P;
        for (int wc = 0; wc < P; wc += 64) {
#pragma unroll
            for (int r = 0; r < 16; ++r) {
                int hh = r * 4 + hh0;
                qsT[ww][hh] = qo[(size_t)(h0 + hh) * P + wc + ww];
                ksT[ww][hh] = ko[(size_t)(v0 + hh) * P + wc + ww];
            }
            __syncthreads();
#pragma unroll 8
            for (int kk = 0; kk < 64; ++kk) {
                float4 qv = *(const float4*)&qsT[kk][ty * 4];
                float4 kv = *(const float4*)&ksT[kk][tx * 4];
                float qa[4] = {qv.x, qv.y, qv.z, qv.w};
                float ka[4] = {kv.x, kv.y, kv.z, kv.w};
#pragma unroll
                for (int i = 0; i < 4; ++i)
#pragma unroll
                    for (int j = 0; j < 4; ++j)
                        acc[i][j] = fmaf(qa[i], ka[j], acc[i][j]);
            }
            __syncthreads();
        }
    }
#pragma unroll
    for (int i = 0; i < 4; ++i) {
        size_t off = (((size_t)z * Bn + b) * P + (h0 + ty * 4 + i)) * P + v0 + tx * 4;
        *(float4*)&epart[off] = make_float4(acc[i][0], acc[i][1], acc[i][2], acc[i][3]);
    }
}

// ---------------------------------------------------------------------------
// Row softmax with split-K reduction; bf16 output for MFMA mix A-operand.
// grid: B*P, block 64.
// ---------------------------------------------------------------------------
template <int P>
__global__ __launch_bounds__(64) void softmax_kernel(
    const float* __restrict__ epart,  // [8][B][P][P]
    __bf16* __restrict__ a)           // [B][P][P] bf16
{
    const int row  = blockIdx.x;
    const int lane = threadIdx.x;
    constexpr int E = P / 64;
    float e[E];
#pragma unroll
    for (int j = 0; j < E; ++j) {
        int v = lane + j * 64;
        float s = 0.f;
#pragma unroll
        for (int z = 0; z < 8; ++z)
            s += epart[((size_t)z * Bn * P + row) * P + v];
        e[j] = s;
    }
    float m = e[0];
#pragma unroll
    for (int j = 1; j < E; ++j) m = fmaxf(m, e[j]);
    for (int off = 32; off > 0; off >>= 1) m = fmaxf(m, __shfl_xor(m, off));
    float sum = 0.f;
#pragma unroll
    for (int j = 0; j < E; ++j) { e[j] = __expf(e[j] - m); sum += e[j]; }
    for (int off = 32; off > 0; off >>= 1) sum += __shfl_xor(sum, off);
    float inv = 1.0f / sum;
#pragma unroll
    for (int j = 0; j < E; ++j)
        a[(size_t)row * P + lane + j * 64] = (__bf16)(e[j] * inv);
}

// ---------------------------------------------------------------------------
// Transpose for the H-branch: X_H[b][w][c][h] = x[b][c][h][w], fp32 -> bf16.
// LDS 32x32 tile. grid: ((P/32)^2, C, B), block 256.
// ---------------------------------------------------------------------------
__global__ __launch_bounds__(256) void transpose_h_kernel(
    const float* __restrict__ x, __bf16* __restrict__ xh, int P)
{
    __shared__ float tile[32][33];
    const int tpb = P >> 5;
    const int tw = blockIdx.x % tpb, th = blockIdx.x / tpb;
    const int c = blockIdx.y, b = blockIdx.z;
    const float* src = x + ((size_t)(b * Cn + c)) * P * P;
    const int i  = threadIdx.x >> 3;
    const int j4 = (threadIdx.x & 7) * 4;
    float4 v = *(const float4*)&src[(size_t)(th * 32 + i) * P + tw * 32 + j4];
    tile[i][j4 + 0] = v.x; tile[i][j4 + 1] = v.y;
    tile[i][j4 + 2] = v.z; tile[i][j4 + 3] = v.w;
    __syncthreads();
    // write row w = tw*32+i, cols h = th*32 + j4..+3
    __bf16* dst = xh + ((size_t)(b * P + tw * 32 + i) * Cn + c) * P + th * 32 + j4;
    bf16x4 o = { (__bf16)tile[j4 + 0][i], (__bf16)tile[j4 + 1][i],
                 (__bf16)tile[j4 + 2][i], (__bf16)tile[j4 + 3][i] };
    *(bf16x4*)dst = o;
}

// ---------------------------------------------------------------------------
// vw fp32 -> bf16 convert. grid 256, block 256 (4 el/thread over 4*C*C).
// ---------------------------------------------------------------------------
__global__ __launch_bounds__(256) void cvt_vw_kernel(
    const float* __restrict__ vw, __bf16* __restrict__ vwb)
{
    int i4 = blockIdx.x * 256 + threadIdx.x;
    float4 v = *(const float4*)&vw[(size_t)i4 * 4];
    bf16x4 o = { (__bf16)v.x, (__bf16)v.y, (__bf16)v.z, (__bf16)v.w };
    *(bf16x4*)&vwb[(size_t)i4 * 4] = o;
}

// ---------------------------------------------------------------------------
// MFMA mix: per batch (b, j), D[m][n] = sum_v a[m][v] * B[v][n=c].
// MODE 0 (over W): j=h, B[v][c] = x[b][c][h][v]      (fp32, convert in staging)
// MODE 1 (over H): j=w, B[v][c] = X_H[b][w][c][v]    (bf16, straight copy)
// Output Y_T[b][pix][c] bf16: MODE 0 pix = j*P+m, MODE 1 pix = m*P+j.
// grid: ((P/BM)*(C/BN), B*P), block 256 (4 waves of 64x64 tiles).
// ---------------------------------------------------------------------------
template <int P, int BM, int BN, int MODE>
__global__ __launch_bounds__(256) void mix_mfma_kernel(
    const __bf16* __restrict__ abf,  // [B][P][P]
    const float*  __restrict__ x,    // [B][C][P][P]
    const __bf16* __restrict__ xh,   // [B][P][C][P]
    __bf16* __restrict__ yt)         // [B][P*P][C]
{
    constexpr int BK  = 32;
    constexpr int LDA = BK + 8;   // 40 bf16 = 80 B rows
    constexpr int WNn = BN / 64;
    __shared__ __bf16 As[BM][LDA];
    __shared__ __bf16 Bs[BN][LDA];
    __shared__ __bf16 Es[4][16][72];
    const int t = threadIdx.x;
    const int z = blockIdx.y;
    const int b = z / P, j = z % P;
    const int mt = blockIdx.x / (Cn / BN);
    const int nt = blockIdx.x % (Cn / BN);
    const int m0 = mt * BM, n0 = nt * BN;
    const int wave = t >> 6, lane = t & 63;
    const int wm = (wave / WNn) * 64, wn = (wave % WNn) * 64;
    const int l16 = lane & 15, quad = lane >> 4;

    floatx4 acc[4][4] = {};

    const __bf16* Ab = abf + (size_t)b * P * P + (size_t)m0 * P;

    for (int kc = 0; kc < P; kc += BK) {
#pragma unroll
        for (int r = 0; r < BM * 4 / 256; ++r) {
            int ch = r * 256 + t;
            int row = ch >> 2, part = ch & 3;
            *(uint4*)&As[row][part * 8] =
                *(const uint4*)&Ab[(size_t)row * P + kc + part * 8];
        }
#pragma unroll
        for (int r = 0; r < BN * 4 / 256; ++r) {
            int ch = r * 256 + t;
            int row = ch >> 2, part = ch & 3;
            if (MODE == 0) {
                const float* src =
                    x + ((size_t)(b * Cn + n0 + row) * P + j) * P + kc + part * 8;
                float4 v0 = *(const float4*)&src[0];
                float4 v1 = *(const float4*)&src[4];
                bf16x8 o = { (__bf16)v0.x, (__bf16)v0.y, (__bf16)v0.z, (__bf16)v0.w,
                             (__bf16)v1.x, (__bf16)v1.y, (__bf16)v1.z, (__bf16)v1.w };
                *(bf16x8*)&Bs[row][part * 8] = o;
            } else {
                *(uint4*)&Bs[row][part * 8] =
                    *(const uint4*)&xh[((size_t)(b * P + j) * Cn + n0 + row) * P + kc + part * 8];
            }
        }
        __syncthreads();
        bf16x8 af[4], bfr[4];
#pragma unroll
        for (int i = 0; i < 4; ++i)
            af[i] = *(const bf16x8*)&As[wm + i * 16 + l16][quad * 8];
#pragma unroll
        for (int j2 = 0; j2 < 4; ++j2)
            bfr[j2] = *(const bf16x8*)&Bs[wn + j2 * 16 + l16][quad * 8];
#pragma unroll
        for (int i = 0; i < 4; ++i)
#pragma unroll
            for (int j2 = 0; j2 < 4; ++j2)
                acc[i][j2] = __builtin_amdgcn_mfma_f32_16x16x32_bf16(
                    af[i], bfr[j2], acc[i][j2], 0, 0, 0);
        __syncthreads();
    }

    // Epilogue: repack each wave's 16x64 row-group through LDS, store bf16x8.
    const size_t outB = (size_t)b * P * P * Cn;
#pragma unroll
    for (int i = 0; i < 4; ++i) {
#pragma unroll
        for (int j2 = 0; j2 < 4; ++j2)
#pragma unroll
            for (int r = 0; r < 4; ++r)
                Es[wave][quad * 4 + r][j2 * 16 + l16] = (__bf16)acc[i][j2][r];
        // wave-private LDS; per-wave DS ordering makes this safe without barrier
#pragma unroll
        for (int s = 0; s < 2; ++s) {
            int ch = s * 64 + lane;
            int row = ch >> 3, part = ch & 7;
            bf16x8 v = *(const bf16x8*)&Es[wave][row][part * 8];
            int m = m0 + wm + i * 16 + row;
            size_t rowOff = (MODE == 0) ? (size_t)(j * P + m) : ((size_t)m * P + j);
            *(bf16x8*)&yt[outB + rowOff * Cn + n0 + wn + part * 8] = v;
        }
    }
}

// ---------------------------------------------------------------------------
// MFMA v-projection + scale + bias + residual epilogue.
// out[c][p] = (first? 2x : out) + s*(sum_k vw[c][k]*Y_T[p][k] + vb[c])
// grid: (Npix/128, 2, B), block 256.
// ---------------------------------------------------------------------------
__global__ __launch_bounds__(256) void vproj_mfma_kernel(
    const __bf16* __restrict__ yt,   // [B][Npix][C]
    const __bf16* __restrict__ vwb,  // [C][C]
    const float* __restrict__ vb,
    const float* __restrict__ x,
    float* __restrict__ out,
    const float* __restrict__ scal, int si, int first, int Npix)
{
    constexpr int BK = 32, LDA = 40;
    __shared__ __bf16 As[128][LDA];
    __shared__ __bf16 Bs[128][LDA];
    const int t  = threadIdx.x;
    const int p0 = blockIdx.x * 128;
    const int c0 = blockIdx.y * 128;
    const int b  = blockIdx.z;
    const int wave = t >> 6, lane = t & 63;
    const int wm = (wave >> 1) * 64, wn = (wave & 1) * 64;
    const int l16 = lane & 15, quad = lane >> 4;
    floatx4 acc[4][4] = {};
    const __bf16* Ab = vwb + (size_t)c0 * Cn;
    const __bf16* Bb = yt + ((size_t)b * Npix + p0) * Cn;

    for (int kc = 0; kc < Cn; kc += BK) {
#pragma unroll
        for (int r = 0; r < 2; ++r) {
            int ch = r * 256 + t;
            int row = ch >> 2, part = ch & 3;
            *(uint4*)&As[row][part * 8] =
                *(const uint4*)&Ab[(size_t)row * Cn + kc + part * 8];
            *(uint4*)&Bs[row][part * 8] =
                *(const uint4*)&Bb[(size_t)row * Cn + kc + part * 8];
        }
        __syncthreads();
        bf16x8 af[4], bfr[4];
#pragma unroll
        for (int i = 0; i < 4; ++i)
            af[i] = *(const bf16x8*)&As[wm + i * 16 + l16][quad * 8];
#pragma unroll
        for (int j2 = 0; j2 < 4; ++j2)
            bfr[j2] = *(const bf16x8*)&Bs[wn + j2 * 16 + l16][quad * 8];
#pragma unroll
        for (int i = 0; i < 4; ++i)
#pragma unroll
            for (int j2 = 0; j2 < 4; ++j2)
                acc[i][j2] = __builtin_amdgcn_mfma_f32_16x16x32_bf16(
                    af[i], bfr[j2], acc[i][j2], 0, 0, 0);
        __syncthreads();
    }

    const float s = scal[si];
#pragma unroll
    for (int i = 0; i < 4; ++i)
#pragma unroll
        for (int r = 0; r < 4; ++r) {
            int c = c0 + wm + i * 16 + quad * 4 + r;
            float bias = vb[c];
            size_t base = ((size_t)(b * Cn + c)) * Npix + p0 + wn + l16;
#pragma unroll
            for (int j2 = 0; j2 < 4; ++j2) {
                size_t idx = base + (size_t)j2 * 16;
                float vres = s * (acc[i][j2][r] + bias);
                vres += first ? 2.f * x[idx] : out[idx];
                out[idx] = vres;
            }
        }
}

struct Bufs {
    __bf16* XH;   // [16][128][256][128] bf16  = 134,217,728 B
    __bf16* YT;   // [16][16384][256]    bf16  = 134,217,728 B (q,k alias head)
    float*  E;    // [8][16][128][128]   fp32  =   8,388,608 B
    __bf16* ABF;  // [16][128][128]      bf16  =     524,288 B
    __bf16* VWB;  // [4][256][256]       bf16  =     524,288 B
    float*  Q;    // alias: YT base
    float*  K;    // alias: YT + 33.5 MB
};

void run_image(const float* x, float* out, int P, int brW, int brH,
               const float* qw, const float* qb, const float* kw, const float* kb,
               const float* vb, const float* sc,
               const Bufs& w, hipStream_t stream)
{
    const int Npix = P * P;
    dim3 blk(256);
    dim3 eg((P / 64) * (P / 64), Bn, 8);

    // ---- half 0: attention over W ----
    qk_proj_kernel<<<dim3(Npix / 128, Bn), blk, 0, stream>>>(
        x, qw + (size_t)brW * C8n * Cn, qb + (size_t)brW * C8n,
        kw + (size_t)brW * C8n * Cn, kb + (size_t)brW * C8n, w.Q, w.K, Npix);
    energy_w_kernel<<<eg, blk, 0, stream>>>(w.Q, w.K, w.E, P, C8n * P / 8);
    if (P == 64) {
        softmax_kernel<64><<<Bn * P, 64, 0, stream>>>(w.E, w.ABF);
        mix_mfma_kernel<64, 64, 256, 0><<<dim3(1, Bn * 64), blk, 0, stream>>>(
            w.ABF, x, w.XH, w.YT);
    } else {
        softmax_kernel<128><<<Bn * P, 64, 0, stream>>>(w.E, w.ABF);
        mix_mfma_kernel<128, 128, 128, 0><<<dim3(2, Bn * 128), blk, 0, stream>>>(
            w.ABF, x, w.XH, w.YT);
    }
    vproj_mfma_kernel<<<dim3(Npix / 128, 2, Bn), blk, 0, stream>>>(
        w.YT, w.VWB + (size_t)brW * Cn * Cn, vb + (size_t)brW * Cn,
        x, out, sc, brW, 1, Npix);

    // ---- half 1: attention over H ----
    transpose_h_kernel<<<dim3((P / 32) * (P / 32), Cn, Bn), blk, 0, stream>>>(
        x, w.XH, P);
    qk_proj_kernel<<<dim3(Npix / 128, Bn), blk, 0, stream>>>(
        x, qw + (size_t)brH * C8n * Cn, qb + (size_t)brH * C8n,
        kw + (size_t)brH * C8n * Cn, kb + (size_t)brH * C8n, w.Q, w.K, Npix);
    energy_h_kernel<<<eg, blk, 0, stream>>>(w.Q, w.K, w.E, P);
    if (P == 64) {
        softmax_kernel<64><<<Bn * P, 64, 0, stream>>>(w.E, w.ABF);
        mix_mfma_kernel<64, 64, 256, 1><<<dim3(1, Bn * 64), blk, 0, stream>>>(
            w.ABF, x, w.XH, w.YT);
    } else {
        softmax_kernel<128><<<Bn * P, 64, 0, stream>>>(w.E, w.ABF);
        mix_mfma_kernel<128, 128, 128, 1><<<dim3(2, Bn * 128), blk, 0, stream>>>(
            w.ABF, x, w.XH, w.YT);
    }
    vproj_mfma_kernel<<<dim3(Npix / 128, 2, Bn), blk, 0, stream>>>(
        w.YT, w.VWB + (size_t)brH * Cn * Cn, vb + (size_t)brH * Cn,
        x, out, sc, brH, 0, Npix);
}

}  // namespace

extern "C" void kernel_launch(void* const* d_in, const int* in_sizes, int n_in,
                              void* d_out, int out_size, void* d_ws, size_t ws_size,
                              hipStream_t stream) {
    (void)in_sizes; (void)n_in; (void)out_size; (void)ws_size;
    const float* tmap = (const float*)d_in[0];
    const float* smap = (const float*)d_in[1];
    const float* qw   = (const float*)d_in[2];
    const float* qb   = (const float*)d_in[3];
    const float* kw   = (const float*)d_in[4];
    const float* kb   = (const float*)d_in[5];
    const float* vw   = (const float*)d_in[6];
    const float* vb   = (const float*)d_in[7];
    const float* sc   = (const float*)d_in[8];

    float* out0 = (float*)d_out;                       // [16,256,64,64]
    float* out1 = out0 + (size_t)16 * 256 * 64 * 64;   // [16,256,128,128]

    // Workspace layout (277,872,640 B total — identical footprint to round 1).
    char* p = (char*)d_ws;
    Bufs w;
    w.XH  = (__bf16*)p;                 p += (size_t)134217728;
    w.YT  = (__bf16*)p;                 p += (size_t)134217728;
    w.E   = (float*)p;                  p += (size_t)8388608;
    w.ABF = (__bf16*)p;                 p += (size_t)524288;
    w.VWB = (__bf16*)p;                 p += (size_t)524288;
    w.Q   = (float*)w.YT;                               // 33.5 MB
    w.K   = (float*)w.YT + (size_t)16 * 32 * 16384;     // 33.5 MB

    cvt_vw_kernel<<<dim3(256), 256, 0, stream>>>(vw, w.VWB);

    // template: P=64, branches 0 (W) and 2 (H)
    run_image(tmap, out0, 64, 0, 2, qw, qb, kw, kb, vb, sc, w, stream);
    // scene: P=128, branches 1 (W) and 3 (H)
    run_image(smap, out1, 128, 1, 3, qw, qb, kw, kb, vb, sc, w, stream);
}